// Round 1
// 550.079 us; speedup vs baseline: 1.1013x; 1.1013x over previous
//
#include <hip/hip_runtime.h>
#include <hip/hip_bf16.h>
#include <stdint.h>

#define TOKENS 8192
#define DIN 4096
#define DOUT 4096
#define RNK 16
#define LORA_SCALE 2.0f

typedef __attribute__((ext_vector_type(8))) __bf16 bf16x8;
typedef __attribute__((ext_vector_type(4))) float f32x4;

__device__ __forceinline__ unsigned short f2bf(float f) {
    union { float f; unsigned int u; } v; v.f = f;
    unsigned int u = v.u;
    unsigned int r = (u + 0x7fffu + ((u >> 16) & 1u)) >> 16;  // RNE
    return (unsigned short)r;
}

__device__ __forceinline__ void async_copy16(const void* g, void* l) {
    __builtin_amdgcn_global_load_lds(
        (const __attribute__((address_space(1))) void*)g,
        (__attribute__((address_space(3))) void*)l,
        16, 0, 0);
}

// ---------------- kernel 1: cast x (fp32) -> bf16 ----------------
__global__ void cast_x_kernel(const float4* __restrict__ x, ushort4* __restrict__ xb) {
    int i = blockIdx.x * blockDim.x + threadIdx.x;
    float4 v = x[i];
    ushort4 o;
    o.x = f2bf(v.x); o.y = f2bf(v.y); o.z = f2bf(v.z); o.w = f2bf(v.w);
    xb[i] = o;
}

// ---------------- kernel 2: W' = bf16(W + 2 * B @ A) ----------------
__global__ void fold_w_kernel(const float* __restrict__ W,
                              const float* __restrict__ lA,
                              const float* __restrict__ lB,
                              ushort* __restrict__ Wb) {
    int o  = blockIdx.y;
    int i0 = (blockIdx.x * blockDim.x + threadIdx.x) * 4;
    __shared__ float sB[RNK];
    if (threadIdx.x < RNK) sB[threadIdx.x] = lB[(size_t)o * RNK + threadIdx.x];
    __syncthreads();
    float4 w = *(const float4*)(W + (size_t)o * DIN + i0);
    float ax = 0.f, ay = 0.f, az = 0.f, aw = 0.f;
#pragma unroll
    for (int r = 0; r < RNK; r++) {
        float4 a = *(const float4*)(lA + (size_t)r * DIN + i0);
        float b = sB[r];
        ax += b * a.x; ay += b * a.y; az += b * a.z; aw += b * a.w;
    }
    ushort4 outv;
    outv.x = f2bf(w.x + LORA_SCALE * ax);
    outv.y = f2bf(w.y + LORA_SCALE * ay);
    outv.z = f2bf(w.z + LORA_SCALE * az);
    outv.w = f2bf(w.w + LORA_SCALE * aw);
    *(ushort4*)(Wb + (size_t)o * DIN + i0) = outv;
}

// ---------------- kernel 3: Y = Xb @ Wb^T + bias ----------------
// 256x256 tile, BK=32, 4-slot LDS ring (128 KiB), deep pipeline:
// stage 3 K-tiles ahead, counted vmcnt(8) at tile boundaries (never 0 in
// steady state), raw s_barrier (no compiler vmcnt drain), setprio around
// the 16-MFMA phase clusters, XCD-bijective block swizzle.
//
// LDS tile geometry: each 16 KB matrix-tile = 128 lines x 128 B; line L holds
// M-rows 2L,2L+1 (each row = 32 bf16 = 4 chunks of 16 B). Chunk for (row r,
// k-chunk q) lives at position p = (q + 4*(r&1)) ^ ((r>>1)&7) within line
// r>>1. Enumeration: every 16-lane ds_read_b128 group hits all 8 bank-quads
// exactly 2x -> 2-way aliasing = free (m136). global_load_lds writes linearly
// (wave base + lane*16), so the inverse permutation is applied to the
// per-lane GLOBAL source address (m173 pattern).
#define BM 256
#define BN 256
#define BK 32
#define NTILES (DIN / BK)      // 128
#define SLOT_U16 16384         // ushorts per ring slot (A 8192 + B 8192) = 32 KB
#define SLOT_BYTES 32768
#define B_OFF_BYTES 16384

__global__ __launch_bounds__(512, 2) void gemm_bias_kernel(
    const ushort* __restrict__ Xb, const ushort* __restrict__ Wb,
    const float* __restrict__ bias, float* __restrict__ Y) {

    __shared__ ushort smem[4 * SLOT_U16];   // 128 KiB ring: 4 K-tiles

    const int tid  = threadIdx.x;
    const int lane = tid & 63;
    const int wave = tid >> 6;

    // XCD-bijective swizzle: 512 wgs, 8 XCDs, 64 contiguous tiles per XCD.
    const int bid  = blockIdx.x;
    const int sbid = (bid & 7) * 64 + (bid >> 3);
    const int m0 = (sbid >> 4) * BM;        // 32 tile rows
    const int n0 = (sbid & 15) * BN;        // 16 tile cols

    const int wm = (wave >> 2) * 128;       // 2 M-wave-groups
    const int wn = (wave & 3) * 64;         // 4 N-wave-groups

    // ---- staging source addresses (inverse-swizzled) ----
    // chunk ci (0..1023) of a 16 KB matrix-tile: L=ci>>3, p=ci&7,
    // u=p^(L&7), h=u>>2, q=u&3 -> global row 2L+h, k-offset q*8.
    auto srcoff = [](int ci) -> size_t {
        const int L = ci >> 3, p = ci & 7;
        const int u = p ^ (L & 7);
        return (size_t)(2 * L + (u >> 2)) * DIN + (size_t)((u & 3) * 8);
    };
    const ushort* pA0 = Xb + (size_t)m0 * DIN + srcoff(tid);
    const ushort* pA1 = Xb + (size_t)m0 * DIN + srcoff(tid + 512);
    const ushort* pB0 = Wb + (size_t)n0 * DIN + srcoff(tid);
    const ushort* pB1 = Wb + (size_t)n0 * DIN + srcoff(tid + 512);

#define STAGE_A(slot) do { \
        ushort* d_ = smem + (slot) * SLOT_U16 + tid * 8; \
        async_copy16(pA0, d_); async_copy16(pA1, d_ + 4096); \
        pA0 += BK; pA1 += BK; } while (0)
#define STAGE_B(slot) do { \
        ushort* d_ = smem + (slot) * SLOT_U16 + 8192 + tid * 8; \
        async_copy16(pB0, d_); async_copy16(pB1, d_ + 4096); \
        pB0 += BK; pB1 += BK; } while (0)

    // ---- fragment-read byte offsets (swizzle-aware), constant per lane ----
    const int lr = lane & 15, qq = lane >> 4;
    const int pp = (qq + 4 * (lr & 1)) ^ ((lr >> 1) & 7);
    const int offA = ((wm >> 1) + (lr >> 1)) * 128 + pp * 16;
    const int offB = ((wn >> 1) + (lr >> 1)) * 128 + pp * 16;
    const char* smemc = (const char*)smem;

    f32x4 acc[8][4] = {};
    bf16x8 af[4], bfr[4];

    // ---- prologue: stage tiles 0,1,2; tile 0 landed, tiles 1,2 in flight ----
    STAGE_A(0); STAGE_B(0);
    STAGE_A(1); STAGE_B(1);
    STAGE_A(2); STAGE_B(2);
    asm volatile("s_waitcnt vmcnt(8)" ::: "memory");
    __builtin_amdgcn_s_barrier();

#pragma unroll 1
    for (int t = 0; t < NTILES; ++t) {
        const char* sa = smemc + (size_t)(t & 3) * SLOT_BYTES;
        const char* sb = sa + B_OFF_BYTES;
        const int  stslot  = (t + 3) & 3;
        const bool doStage = (t + 3 < NTILES);

        // ---- phase 0: acc[0..3][0..3] ----
#pragma unroll
        for (int f = 0; f < 4; f++) af[f]  = *(const bf16x8*)(sa + offA + f * 1024);
#pragma unroll
        for (int f = 0; f < 4; f++) bfr[f] = *(const bf16x8*)(sb + offB + f * 1024);
        if (doStage) STAGE_A(stslot);
        __builtin_amdgcn_s_barrier();
        asm volatile("s_waitcnt lgkmcnt(0)" ::: "memory");
        __builtin_amdgcn_s_setprio(1);
#pragma unroll
        for (int mf = 0; mf < 4; mf++)
#pragma unroll
            for (int nf = 0; nf < 4; nf++)
                acc[mf][nf] = __builtin_amdgcn_mfma_f32_16x16x32_bf16(
                    af[mf], bfr[nf], acc[mf][nf], 0, 0, 0);
        __builtin_amdgcn_s_setprio(0);
        __builtin_amdgcn_s_barrier();

        // ---- phase 1: acc[4..7][0..3] (B fragments reused from regs) ----
#pragma unroll
        for (int f = 0; f < 4; f++) af[f] = *(const bf16x8*)(sa + offA + (4 + f) * 1024);
        if (doStage) STAGE_B(stslot);
        __builtin_amdgcn_s_barrier();
        asm volatile("s_waitcnt lgkmcnt(0)" ::: "memory");
        __builtin_amdgcn_s_setprio(1);
#pragma unroll
        for (int mf = 0; mf < 4; mf++)
#pragma unroll
            for (int nf = 0; nf < 4; nf++)
                acc[4 + mf][nf] = __builtin_amdgcn_mfma_f32_16x16x32_bf16(
                    af[mf], bfr[nf], acc[4 + mf][nf], 0, 0, 0);
        __builtin_amdgcn_s_setprio(0);

        // ---- K-tile boundary: counted vmcnt, barrier. Steady state leaves
        //      tiles t+2,t+3 (8 loads/wave) in flight; epilogue 8->4->0. ----
        if (t + 3 < NTILES) {
            asm volatile("s_waitcnt vmcnt(8)" ::: "memory");
            __builtin_amdgcn_s_barrier();
        } else if (t + 3 == NTILES) {
            asm volatile("s_waitcnt vmcnt(4)" ::: "memory");
            __builtin_amdgcn_s_barrier();
        } else if (t + 2 == NTILES) {
            asm volatile("s_waitcnt vmcnt(0)" ::: "memory");
            __builtin_amdgcn_s_barrier();
        }
        // t == NTILES-1: no successor, fall through to epilogue
    }

    // ---- epilogue: C/D layout col=lane&15, row=(lane>>4)*4+reg [m89/m91] ----
    const int col  = lane & 15;
    const int qrow = (lane >> 4) * 4;
#pragma unroll
    for (int nf = 0; nf < 4; nf++) {
        const int n = n0 + wn + nf * 16 + col;
        const float bv = bias[n];
#pragma unroll
        for (int mf = 0; mf < 8; mf++) {
            const int m = m0 + wm + mf * 16 + qrow;
            float* yp = Y + (size_t)m * DOUT + n;
            yp[0]                  = acc[mf][nf].x + bv;
            yp[(size_t)DOUT]       = acc[mf][nf].y + bv;
            yp[2 * (size_t)DOUT]   = acc[mf][nf].z + bv;
            yp[3 * (size_t)DOUT]   = acc[mf][nf].w + bv;
        }
    }
#undef STAGE_A
#undef STAGE_B
}

extern "C" void kernel_launch(void* const* d_in, const int* in_sizes, int n_in,
                              void* d_out, int out_size, void* d_ws, size_t ws_size,
                              hipStream_t stream) {
    const float* x    = (const float*)d_in[0];
    const float* W    = (const float*)d_in[1];
    const float* bias = (const float*)d_in[2];
    const float* lA   = (const float*)d_in[3];
    const float* lB   = (const float*)d_in[4];
    float* Y = (float*)d_out;

    ushort* xb = (ushort*)d_ws;                       // 64 MB
    ushort* wb = xb + (size_t)TOKENS * DIN;           // +32 MB

    cast_x_kernel<<<(TOKENS * DIN / 4) / 256, 256, 0, stream>>>(
        (const float4*)x, (ushort4*)xb);
    fold_w_kernel<<<dim3(DIN / (256 * 4), DOUT), 256, 0, stream>>>(W, lA, lB, wb);
    gemm_bias_kernel<<<dim3((TOKENS / BM) * (DOUT / BN)), 512, 0, stream>>>(
        xb, wb, bias, Y);
}